// Round 8
// baseline (127.055 us; speedup 1.0000x reference)
//
#include <hip/hip_runtime.h>
#include <hip/hip_bf16.h>

#define SEQ 1024
#define DK 8
#define NH 12
#define BATCH 8
#define NQ 96
#define ED 768

typedef __attribute__((ext_vector_type(8))) _Float16 half8;
typedef __attribute__((ext_vector_type(2))) __fp16 fp16x2;
typedef __attribute__((ext_vector_type(4))) float floatx4;
typedef __attribute__((ext_vector_type(2))) unsigned uint2v;

__device__ __forceinline__ float fast_exp2(float x) {
#if __has_builtin(__builtin_amdgcn_exp2f)
    return __builtin_amdgcn_exp2f(x);
#else
    return exp2f(x);
#endif
}

// Pack two fp32 -> fp16x2 in one v_cvt_pkrtz_f16_f32, as a 32-bit word.
__device__ __forceinline__ unsigned pkh(float lo, float hi) {
    union { fp16x2 h; unsigned u; } v;
    v.h = __builtin_amdgcn_cvt_pkrtz(lo, hi);
    return v.u;
}

// ---------------------------------------------------------------------------
// Fused quantum-attention via fp16 MFMA (R6-verified structure).
// R7 change: one block = (b, h, 256-query chunk), grid 4x12x8 = 384 blocks
// (single residency round at 2 blocks/CU).  Each wave owns TWO 16-query
// tiles that share the per-window key A-frags and V B-frag (half the LDS
// reads, half the staging redundancy) and form two independent
// QK->exp->PV dependency chains (2x ILP in the latency-bound chain).
//
// P round-trips through LDS between QK^T and PV (m120-verified transform):
// score D-values written at explicit (query,key) addresses (stride 36
// halfs), PV A-frag read back by address.  Denominator: fp32 lacc over the
// same e-values, quad-reduced via shfl_xor(16,32).
//
// LDS:
//   qv  (1024x8 fp16, scaled by sqrt(log2e/sqrt8)) — feeds A and B of QK^T.
//   qvt (tiled V'): (win,q,n,j) -> win*512 + q*128 + n*8 + j; PV B-frag is
//        one contiguous ds_read_b128 per lane (cols 8..15 zero).
//   pt  per-wave P^T tile: addr = query*36 + key; reused by both q-tiles
//        within a window (same-wave DS ops are in-order => safe).
// ---------------------------------------------------------------------------
__global__ __launch_bounds__(512) void attn_kernel(
    const float* __restrict__ x, const float* __restrict__ theta,
    _Float16* __restrict__ attn /* (BATCH*SEQ, NQ) fp16 */)
{
    __shared__ __align__(16) _Float16 qv[SEQ * DK];    // 16 KB
    __shared__ __align__(16) _Float16 qvt[32 * 512];   // 32 KB
    __shared__ __align__(16) _Float16 pt[8 * 576];     // 9 KB

    const int chunk = blockIdx.x;   // 0..3  (256 queries)
    const int h     = blockIdx.y;
    const int b     = blockIdx.z;
    const int tid   = threadIdx.x;

    const float SQS = 0.71419170f;  // sqrt(log2(e)/sqrt(8))

    float ct[8];
    #pragma unroll
    for (int k = 0; k < 8; ++k) ct[k] = __cosf(theta[h * DK + k]);

    // ---- stage q into qv (scaled) and qvt (tiled, unscaled) ----
    #pragma unroll
    for (int it = 0; it < 2; ++it) {
        const int s = tid + it * 512;
        const float* xp = x + ((size_t)(b * SEQ + s)) * ED + h * DK;
        const float4 v0 = *(const float4*)xp;
        const float4 v1 = *(const float4*)(xp + 4);
        float q[8];
        q[0] = __cosf(v0.x) * ct[0]; q[1] = __cosf(v0.y) * ct[1];
        q[2] = __cosf(v0.z) * ct[2]; q[3] = __cosf(v0.w) * ct[3];
        q[4] = __cosf(v1.x) * ct[4]; q[5] = __cosf(v1.y) * ct[5];
        q[6] = __cosf(v1.z) * ct[6]; q[7] = __cosf(v1.w) * ct[7];
        union { half8 v; _Float16 e[8]; } row;
        #pragma unroll
        for (int k = 0; k < 8; ++k) row.e[k] = (_Float16)(q[k] * SQS);
        *(half8*)&qv[s * DK] = row.v;
        const int e0 = (s >> 5) * 512 + ((s >> 3) & 3) * 128 + (s & 7);
        #pragma unroll
        for (int k = 0; k < 8; ++k) qvt[e0 + k * 8] = (_Float16)q[k];
    }
    // ---- V' columns 8..15: zeros (B-frag lanes 8..15 read them) ----
    {
        const int ww = tid >> 4, qq = (tid >> 2) & 3, np = tid & 3;
        const int n0 = 8 + np * 2;
        const int e  = ww * 512 + qq * 128 + n0 * 8;
        #pragma unroll
        for (int j = 0; j < 8; ++j) { qvt[e + j] = (_Float16)0.0f; qvt[e + 8 + j] = (_Float16)0.0f; }
    }
    __syncthreads();

    const int w    = tid >> 6;       // wave 0..7
    const int lane = tid & 63;
    const int l15  = lane & 15;
    const int qt   = lane >> 4;
    const int m0w  = chunk * 256 + w * 32;

    _Float16* zp = &qvt[72];         // 16 zero bytes (win0,q0,n=9), 16B-aligned
    _Float16* myp = &pt[w * 576];    // this wave's P^T tile

    // Score MFMA B-frags: Q rows of the two 16-query tiles (quad 0 only).
    const half8 bfm0 = *(const half8*)((qt == 0) ? &qv[(m0w + l15) * DK]      : zp);
    const half8 bfm1 = *(const half8*)((qt == 0) ? &qv[(m0w + 16 + l15) * DK] : zp);

    const _Float16* pa0 = (qt == 0) ? &qv[l15 * DK]        : zp;
    const _Float16* pa1 = (qt == 0) ? &qv[(16 + l15) * DK] : zp;
    const int ainc = (qt == 0) ? 32 * DK : 0;        // 32 key-rows per window
    const _Float16* pv = &qvt[qt * 128 + l15 * 8];

    // P^T addresses: lane's d-values are scores(key = 16*half + qt*4+r,
    // query = l15)  [R6-verified].
    _Float16* pw0 = &myp[l15 * 36 + qt * 4];         // keys qt*4 + 0..3
    _Float16* pw1 = pw0 + 16;                        // keys 16 + qt*4 + 0..3
    const _Float16* pr = &myp[l15 * 36 + qt * 8];    // A-frag: keys qt*8+0..7

    floatx4 acc0 = {0.f, 0.f, 0.f, 0.f};
    floatx4 acc1 = {0.f, 0.f, 0.f, 0.f};
    float lacc0 = 0.f, lacc1 = 0.f;
    const floatx4 zc = {0.f, 0.f, 0.f, 0.f};

    #pragma unroll 2
    for (int win = 0; win < 32; ++win) {
        const half8 af0 = *(const half8*)pa0;  pa0 += ainc;
        const half8 af1 = *(const half8*)pa1;  pa1 += ainc;
        const half8 vf  = *(const half8*)pv;   pv += 512;

        // ---- q-tile 0 ----
        {
            floatx4 d0 = __builtin_amdgcn_mfma_f32_16x16x32_f16(af0, bfm0, zc, 0, 0, 0);
            floatx4 d1 = __builtin_amdgcn_mfma_f32_16x16x32_f16(af1, bfm0, zc, 0, 0, 0);
            const float e00 = fast_exp2(d0[0]), e01 = fast_exp2(d0[1]);
            const float e02 = fast_exp2(d0[2]), e03 = fast_exp2(d0[3]);
            const float e10 = fast_exp2(d1[0]), e11 = fast_exp2(d1[1]);
            const float e12 = fast_exp2(d1[2]), e13 = fast_exp2(d1[3]);
            lacc0 += ((e00 + e01) + (e02 + e03)) + ((e10 + e11) + (e12 + e13));
            *(uint2v*)pw0 = (uint2v){pkh(e00, e01), pkh(e02, e03)};
            *(uint2v*)pw1 = (uint2v){pkh(e10, e11), pkh(e12, e13)};
            const half8 paf = *(const half8*)pr;
            acc0 = __builtin_amdgcn_mfma_f32_16x16x32_f16(paf, vf, acc0, 0, 0, 0);
        }
        // ---- q-tile 1 (reuses af0/af1/vf; same pt addresses, in-order DS) ----
        {
            floatx4 d0 = __builtin_amdgcn_mfma_f32_16x16x32_f16(af0, bfm1, zc, 0, 0, 0);
            floatx4 d1 = __builtin_amdgcn_mfma_f32_16x16x32_f16(af1, bfm1, zc, 0, 0, 0);
            const float e00 = fast_exp2(d0[0]), e01 = fast_exp2(d0[1]);
            const float e02 = fast_exp2(d0[2]), e03 = fast_exp2(d0[3]);
            const float e10 = fast_exp2(d1[0]), e11 = fast_exp2(d1[1]);
            const float e12 = fast_exp2(d1[2]), e13 = fast_exp2(d1[3]);
            lacc1 += ((e00 + e01) + (e02 + e03)) + ((e10 + e11) + (e12 + e13));
            *(uint2v*)pw0 = (uint2v){pkh(e00, e01), pkh(e02, e03)};
            *(uint2v*)pw1 = (uint2v){pkh(e10, e11), pkh(e12, e13)};
            const half8 paf = *(const half8*)pr;
            acc1 = __builtin_amdgcn_mfma_f32_16x16x32_f16(paf, vf, acc1, 0, 0, 0);
        }
    }

    // Quad-reduce denominators: L[query l15] in every lane.
    lacc0 += __shfl_xor(lacc0, 16);
    lacc0 += __shfl_xor(lacc0, 32);
    lacc1 += __shfl_xor(lacc1, 16);
    lacc1 += __shfl_xor(lacc1, 32);

    // Row m = qt*4+r is query (m0w [+16]) + qt*4+r; L[m] at lanes l15 = qt*4+r.
    #pragma unroll
    for (int r = 0; r < 4; ++r) {
        const float lsum = __shfl(lacc0, qt * 4 + r);
        const float val  = acc0[r] * __builtin_amdgcn_rcpf(lsum);
        if (l15 < 8) {
            const int m = m0w + qt * 4 + r;
            attn[((size_t)(b * SEQ + m)) * NQ + h * DK + l15] = (_Float16)val;
        }
    }
    #pragma unroll
    for (int r = 0; r < 4; ++r) {
        const float lsum = __shfl(lacc1, qt * 4 + r);
        const float val  = acc1[r] * __builtin_amdgcn_rcpf(lsum);
        if (l15 < 8) {
            const int m = m0w + 16 + qt * 4 + r;
            attn[((size_t)(b * SEQ + m)) * NQ + h * DK + l15] = (_Float16)val;
        }
    }
}

// ---------------------------------------------------------------------------
// W (768x96 fp32) -> fp16.
// ---------------------------------------------------------------------------
__global__ __launch_bounds__(256) void wconv_kernel(
    const float* __restrict__ W, _Float16* __restrict__ Wh)
{
    const int i = blockIdx.x * 256 + threadIdx.x;   // float4 index
    const float4 v = ((const float4*)W)[i];
    union { unsigned u[2]; double d; } o;
    o.u[0] = pkh(v.x, v.y);
    o.u[1] = pkh(v.z, v.w);
    ((double*)Wh)[i] = o.d;
}

// ---------------------------------------------------------------------------
// out = attn_fp16 @ Wh^T via 16x16x32 fp16 MFMA (R6/R7-verified).
// ---------------------------------------------------------------------------
__global__ __launch_bounds__(256) void proj_kernel(
    const _Float16* __restrict__ attn, const _Float16* __restrict__ Wh,
    float* __restrict__ out)
{
    const int tid  = threadIdx.x;
    const int w    = tid >> 6;
    const int lane = tid & 63;
    const int l15  = lane & 15;
    const int quad = lane >> 4;

    const int m0 = blockIdx.y * 64 + w * 16;
    const int n0 = blockIdx.x * 64;

    const size_t abase = ((size_t)(m0 + l15)) * NQ + quad * 8;
    half8 af0 = *(const half8*)(attn + abase);
    half8 af1 = *(const half8*)(attn + abase + 32);
    half8 af2 = *(const half8*)(attn + abase + 64);

    floatx4 acc[4];
    #pragma unroll
    for (int c = 0; c < 4; ++c) acc[c] = (floatx4){0.f, 0.f, 0.f, 0.f};

    #pragma unroll
    for (int c = 0; c < 4; ++c) {
        const size_t bbase = ((size_t)(n0 + c * 16 + l15)) * NQ + quad * 8;
        half8 b0 = *(const half8*)(Wh + bbase);
        half8 b1 = *(const half8*)(Wh + bbase + 32);
        half8 b2 = *(const half8*)(Wh + bbase + 64);
        acc[c] = __builtin_amdgcn_mfma_f32_16x16x32_f16(af0, b0, acc[c], 0, 0, 0);
        acc[c] = __builtin_amdgcn_mfma_f32_16x16x32_f16(af1, b1, acc[c], 0, 0, 0);
        acc[c] = __builtin_amdgcn_mfma_f32_16x16x32_f16(af2, b2, acc[c], 0, 0, 0);
    }

    #pragma unroll
    for (int c = 0; c < 4; ++c)
        #pragma unroll
        for (int r = 0; r < 4; ++r)
            out[((size_t)(m0 + quad * 4 + r)) * ED + n0 + c * 16 + l15] = acc[c][r];
}

extern "C" void kernel_launch(void* const* d_in, const int* in_sizes, int n_in,
                              void* d_out, int out_size, void* d_ws, size_t ws_size,
                              hipStream_t stream) {
    const float* x     = (const float*)d_in[0];
    const float* theta = (const float*)d_in[1];
    const float* W     = (const float*)d_in[2];
    float* out = (float*)d_out;

    _Float16* attn = (_Float16*)d_ws;                                        // 1.5 MB
    _Float16* Wh   = (_Float16*)((char*)d_ws + (size_t)BATCH * SEQ * NQ * 2);

    wconv_kernel<<<dim3(ED * NQ / 4 / 256), 256, 0, stream>>>(W, Wh);
    attn_kernel<<<dim3(4, NH, BATCH), 512, 0, stream>>>(x, theta, attn);
    proj_kernel<<<dim3(ED / 64, (BATCH * SEQ) / 64), 256, 0, stream>>>(attn, Wh, out);
}

// Round 9
// 120.001 us; speedup vs baseline: 1.0588x; 1.0588x over previous
//
#include <hip/hip_runtime.h>
#include <hip/hip_bf16.h>

#define SEQ 1024
#define DK 8
#define NH 12
#define BATCH 8
#define NQ 96
#define ED 768

typedef __attribute__((ext_vector_type(8))) _Float16 half8;
typedef __attribute__((ext_vector_type(2))) __fp16 fp16x2;
typedef __attribute__((ext_vector_type(4))) float floatx4;
typedef __attribute__((ext_vector_type(2))) unsigned uint2v;

__device__ __forceinline__ float fast_exp2(float x) {
#if __has_builtin(__builtin_amdgcn_exp2f)
    return __builtin_amdgcn_exp2f(x);
#else
    return exp2f(x);
#endif
}

// Pack two fp32 -> fp16x2 in one v_cvt_pkrtz_f16_f32, as a 32-bit word.
__device__ __forceinline__ unsigned pkh(float lo, float hi) {
    union { fp16x2 h; unsigned u; } v;
    v.h = __builtin_amdgcn_cvt_pkrtz(lo, hi);
    return v.u;
}

// ---------------------------------------------------------------------------
// Fused quantum-attention via fp16 MFMA (R6/R7-verified addressing).
// One block = (b, h, 128-query chunk), 512 threads = 8 waves, one 16-query
// tile per wave, 1024 keys in 32-key windows.  Scores bounded => no softmax
// max/rescale.  P round-trips through LDS (m120-verified transform).
//
// R9 change: PV is software-pipelined one window behind QK using the
// in-order per-wave DS queue: each iteration issues the pt READ (window
// w-1's P) BEFORE the pt WRITE (window w), so the read returns the old
// data and the write->wait->read round-trip (~240 cyc) leaves the
// loop-carried critical path.  Single pt buffer, addresses byte-identical
// to the passing R6/R7 kernels.
//
// LDS:
//   qv  (1024x8 fp16, scaled by sqrt(log2e/sqrt8)) — feeds A and B of QK^T.
//   qvt (tiled V'): (win,q,n,j) -> win*512 + q*128 + n*8 + j; PV B-frag is
//        one contiguous ds_read_b128 per lane (cols 8..15 zero).
//   pt  per-wave P^T tile: addr = query*36 + key.
// ---------------------------------------------------------------------------
__global__ __launch_bounds__(512) void attn_kernel(
    const float* __restrict__ x, const float* __restrict__ theta,
    _Float16* __restrict__ attn /* (BATCH*SEQ, NQ) fp16 */)
{
    __shared__ __align__(16) _Float16 qv[SEQ * DK];    // 16 KB
    __shared__ __align__(16) _Float16 qvt[32 * 512];   // 32 KB
    __shared__ __align__(16) _Float16 pt[8 * 576];     // 9 KB

    const int chunk = blockIdx.x;   // 0..7  (128 queries)
    const int h     = blockIdx.y;
    const int b     = blockIdx.z;
    const int tid   = threadIdx.x;

    const float SQS = 0.71419170f;  // sqrt(log2(e)/sqrt(8))

    float ct[8];
    #pragma unroll
    for (int k = 0; k < 8; ++k) ct[k] = __cosf(theta[h * DK + k]);

    // ---- stage q into qv (scaled) and qvt (tiled, unscaled) ----
    #pragma unroll
    for (int it = 0; it < 2; ++it) {
        const int s = tid + it * 512;
        const float* xp = x + ((size_t)(b * SEQ + s)) * ED + h * DK;
        const float4 v0 = *(const float4*)xp;
        const float4 v1 = *(const float4*)(xp + 4);
        float q[8];
        q[0] = __cosf(v0.x) * ct[0]; q[1] = __cosf(v0.y) * ct[1];
        q[2] = __cosf(v0.z) * ct[2]; q[3] = __cosf(v0.w) * ct[3];
        q[4] = __cosf(v1.x) * ct[4]; q[5] = __cosf(v1.y) * ct[5];
        q[6] = __cosf(v1.z) * ct[6]; q[7] = __cosf(v1.w) * ct[7];
        union { half8 v; _Float16 e[8]; } row;
        #pragma unroll
        for (int k = 0; k < 8; ++k) row.e[k] = (_Float16)(q[k] * SQS);
        *(half8*)&qv[s * DK] = row.v;
        const int e0 = (s >> 5) * 512 + ((s >> 3) & 3) * 128 + (s & 7);
        #pragma unroll
        for (int k = 0; k < 8; ++k) qvt[e0 + k * 8] = (_Float16)q[k];
    }
    // ---- V' columns 8..15: zeros (B-frag lanes 8..15 read them) ----
    {
        const int ww = tid >> 4, qq = (tid >> 2) & 3, np = tid & 3;
        const int n0 = 8 + np * 2;
        const int e  = ww * 512 + qq * 128 + n0 * 8;
        #pragma unroll
        for (int j = 0; j < 8; ++j) { qvt[e + j] = (_Float16)0.0f; qvt[e + 8 + j] = (_Float16)0.0f; }
    }
    __syncthreads();

    const int w    = tid >> 6;       // wave 0..7
    const int lane = tid & 63;
    const int l15  = lane & 15;
    const int qt   = lane >> 4;
    const int m0w  = chunk * 128 + w * 16;

    _Float16* zp = &qvt[72];         // 16 zero bytes (win0,q0,n=9), 16B-aligned
    _Float16* myp = &pt[w * 576];    // this wave's P^T tile

    // Score MFMA B-frag: Q rows of my 16-query tile (quad 0 only).
    const half8 bfm = *(const half8*)((qt == 0) ? &qv[(m0w + l15) * DK] : zp);

    const _Float16* pa0 = (qt == 0) ? &qv[l15 * DK]        : zp;
    const _Float16* pa1 = (qt == 0) ? &qv[(16 + l15) * DK] : zp;
    const int ainc = (qt == 0) ? 32 * DK : 0;        // 32 key-rows per window
    const _Float16* pv = &qvt[qt * 128 + l15 * 8];

    // P^T addresses (R6-verified): lane's d-values are scores(key =
    // 16*half + qt*4+r, query = l15).
    _Float16* pw0 = &myp[l15 * 36 + qt * 4];         // keys qt*4 + 0..3
    _Float16* pw1 = pw0 + 16;                        // keys 16 + qt*4 + 0..3
    const _Float16* pr = &myp[l15 * 36 + qt * 8];    // A-frag: keys qt*8+0..7

    floatx4 acc = {0.f, 0.f, 0.f, 0.f};
    float lacc = 0.f;                 // fp32 softmax denominator partial
    const floatx4 zc = {0.f, 0.f, 0.f, 0.f};

    // ---- window 0 (prologue): QK + exp + write pt, no PV yet ----
    {
        const half8 af0 = *(const half8*)pa0;  pa0 += ainc;
        const half8 af1 = *(const half8*)pa1;  pa1 += ainc;
        floatx4 d0 = __builtin_amdgcn_mfma_f32_16x16x32_f16(af0, bfm, zc, 0, 0, 0);
        floatx4 d1 = __builtin_amdgcn_mfma_f32_16x16x32_f16(af1, bfm, zc, 0, 0, 0);
        const float e00 = fast_exp2(d0[0]), e01 = fast_exp2(d0[1]);
        const float e02 = fast_exp2(d0[2]), e03 = fast_exp2(d0[3]);
        const float e10 = fast_exp2(d1[0]), e11 = fast_exp2(d1[1]);
        const float e12 = fast_exp2(d1[2]), e13 = fast_exp2(d1[3]);
        lacc += ((e00 + e01) + (e02 + e03)) + ((e10 + e11) + (e12 + e13));
        *(uint2v*)pw0 = (uint2v){pkh(e00, e01), pkh(e02, e03)};
        *(uint2v*)pw1 = (uint2v){pkh(e10, e11), pkh(e12, e13)};
    }

    // ---- windows 1..31: PV lags QK by one window ----
    #pragma unroll 2
    for (int win = 1; win < 32; ++win) {
        // Previous window's P and V: reads issued BEFORE this window's pt
        // write (in-order DS queue => they return the old/correct data).
        const half8 paf = *(const half8*)pr;
        const half8 vf  = *(const half8*)pv;   pv += 512;

        const half8 af0 = *(const half8*)pa0;  pa0 += ainc;
        const half8 af1 = *(const half8*)pa1;  pa1 += ainc;
        floatx4 d0 = __builtin_amdgcn_mfma_f32_16x16x32_f16(af0, bfm, zc, 0, 0, 0);
        floatx4 d1 = __builtin_amdgcn_mfma_f32_16x16x32_f16(af1, bfm, zc, 0, 0, 0);

        const float e00 = fast_exp2(d0[0]), e01 = fast_exp2(d0[1]);
        const float e02 = fast_exp2(d0[2]), e03 = fast_exp2(d0[3]);
        const float e10 = fast_exp2(d1[0]), e11 = fast_exp2(d1[1]);
        const float e12 = fast_exp2(d1[2]), e13 = fast_exp2(d1[3]);
        lacc += ((e00 + e01) + (e02 + e03)) + ((e10 + e11) + (e12 + e13));

        *(uint2v*)pw0 = (uint2v){pkh(e00, e01), pkh(e02, e03)};
        *(uint2v*)pw1 = (uint2v){pkh(e10, e11), pkh(e12, e13)};

        acc = __builtin_amdgcn_mfma_f32_16x16x32_f16(paf, vf, acc, 0, 0, 0);
    }

    // ---- epilogue: last window's PV ----
    {
        const half8 paf = *(const half8*)pr;
        const half8 vf  = *(const half8*)pv;
        acc = __builtin_amdgcn_mfma_f32_16x16x32_f16(paf, vf, acc, 0, 0, 0);
    }

    // Quad-reduce the denominator: L[query l15] in every lane.
    lacc += __shfl_xor(lacc, 16);
    lacc += __shfl_xor(lacc, 32);

    // Row m = qt*4+r is query m0w+qt*4+r; L[m] sits at lanes with l15 = m.
    #pragma unroll
    for (int r = 0; r < 4; ++r) {
        const float lsum = __shfl(lacc, qt * 4 + r);
        const float val  = acc[r] * __builtin_amdgcn_rcpf(lsum);
        if (l15 < 8) {
            const int m = m0w + qt * 4 + r;
            attn[((size_t)(b * SEQ + m)) * NQ + h * DK + l15] = (_Float16)val;
        }
    }
}

// ---------------------------------------------------------------------------
// W (768x96 fp32) -> fp16.
// ---------------------------------------------------------------------------
__global__ __launch_bounds__(256) void wconv_kernel(
    const float* __restrict__ W, _Float16* __restrict__ Wh)
{
    const int i = blockIdx.x * 256 + threadIdx.x;   // float4 index
    const float4 v = ((const float4*)W)[i];
    union { unsigned u[2]; double d; } o;
    o.u[0] = pkh(v.x, v.y);
    o.u[1] = pkh(v.z, v.w);
    ((double*)Wh)[i] = o.d;
}

// ---------------------------------------------------------------------------
// out = attn_fp16 @ Wh^T via 16x16x32 fp16 MFMA (R6/R7-verified).
// ---------------------------------------------------------------------------
__global__ __launch_bounds__(256) void proj_kernel(
    const _Float16* __restrict__ attn, const _Float16* __restrict__ Wh,
    float* __restrict__ out)
{
    const int tid  = threadIdx.x;
    const int w    = tid >> 6;
    const int lane = tid & 63;
    const int l15  = lane & 15;
    const int quad = lane >> 4;

    const int m0 = blockIdx.y * 64 + w * 16;
    const int n0 = blockIdx.x * 64;

    const size_t abase = ((size_t)(m0 + l15)) * NQ + quad * 8;
    half8 af0 = *(const half8*)(attn + abase);
    half8 af1 = *(const half8*)(attn + abase + 32);
    half8 af2 = *(const half8*)(attn + abase + 64);

    floatx4 acc[4];
    #pragma unroll
    for (int c = 0; c < 4; ++c) acc[c] = (floatx4){0.f, 0.f, 0.f, 0.f};

    #pragma unroll
    for (int c = 0; c < 4; ++c) {
        const size_t bbase = ((size_t)(n0 + c * 16 + l15)) * NQ + quad * 8;
        half8 b0 = *(const half8*)(Wh + bbase);
        half8 b1 = *(const half8*)(Wh + bbase + 32);
        half8 b2 = *(const half8*)(Wh + bbase + 64);
        acc[c] = __builtin_amdgcn_mfma_f32_16x16x32_f16(af0, b0, acc[c], 0, 0, 0);
        acc[c] = __builtin_amdgcn_mfma_f32_16x16x32_f16(af1, b1, acc[c], 0, 0, 0);
        acc[c] = __builtin_amdgcn_mfma_f32_16x16x32_f16(af2, b2, acc[c], 0, 0, 0);
    }

    #pragma unroll
    for (int c = 0; c < 4; ++c)
        #pragma unroll
        for (int r = 0; r < 4; ++r)
            out[((size_t)(m0 + quad * 4 + r)) * ED + n0 + c * 16 + l15] = acc[c][r];
}

extern "C" void kernel_launch(void* const* d_in, const int* in_sizes, int n_in,
                              void* d_out, int out_size, void* d_ws, size_t ws_size,
                              hipStream_t stream) {
    const float* x     = (const float*)d_in[0];
    const float* theta = (const float*)d_in[1];
    const float* W     = (const float*)d_in[2];
    float* out = (float*)d_out;

    _Float16* attn = (_Float16*)d_ws;                                        // 1.5 MB
    _Float16* Wh   = (_Float16*)((char*)d_ws + (size_t)BATCH * SEQ * NQ * 2);

    wconv_kernel<<<dim3(ED * NQ / 4 / 256), 256, 0, stream>>>(W, Wh);
    attn_kernel<<<dim3(8, NH, BATCH), 512, 0, stream>>>(x, theta, attn);
    proj_kernel<<<dim3(ED / 64, (BATCH * SEQ) / 64), 256, 0, stream>>>(attn, Wh, out);
}